// Round 10
// baseline (156.970 us; speedup 1.0000x reference)
//
#include <hip/hip_runtime.h>

// FeatureExpansion: per (b, ol) stride of 10x32 f32 -> 1120 f32 outputs
// [std(32) | z(32) | ld(32) | ret(32) | covf(496) | corrf(496)]
// One wave per stride; 4 waves per block; wave-local sync only.
//
// HARD-WON RULE (R5/R6/R7, ~10x HBM traffic amplification): keep
// __launch_bounds__(256,4) AND LDS at 24,064 B/block (6 blocks/CU).
// 7-8 resident blocks/CU blew up FETCH+WRITE ~10x regardless of store
// structure. Do not slim LDS, do not raise the LB waves/EU arg.
//
// R9 lesson: register prefetch / persistent waves = neutral (latency is
// already hidden by 24 waves/CU). Flat grid (R8) is best.
// This round's single variable: stores are PLAIN (L2-evict streaming like
// the 6.5 TB/s fill kernels) instead of nontemporal. NT loads kept.

typedef float fx4 __attribute__((ext_vector_type(4)));

constexpr int S      = 10;
constexpr int F      = 32;
constexpr int NPAIR  = 496;     // F*(F-1)/2
constexpr int OUTW   = 1120;    // 4*F + 2*NPAIR
constexpr int WAVES  = 4;
// per-wave LDS slice (floats): raw[320] | mu[32] | rs[32] | stage[1120]
constexpr int SLICE  = 320 + 64 + OUTW;   // 1504 floats = 6016 B; block = 24,064 B

// Wave-local barrier (each wave touches only its own LDS slice).
__device__ __forceinline__ void wave_sync() {
    asm volatile("s_waitcnt lgkmcnt(0)" ::: "memory");
    __builtin_amdgcn_sched_barrier(0);
}
__device__ __forceinline__ float fast_rcp(float x) { return __builtin_amdgcn_rcpf(x); }

__global__ __launch_bounds__(256, 4)
void fe_kernel(const float* __restrict__ in, float* __restrict__ out, int nstrides)
{
    __shared__ float lds[WAVES * SLICE];

    const int wv   = threadIdx.x >> 6;
    const int lane = threadIdx.x & 63;
    int sid = blockIdx.x * WAVES + wv;
    if (sid >= nstrides) sid = nstrides - 1;   // grid divides exactly for this shape

    float* raw   = &lds[wv * SLICE];   // 10x32 raw tile
    float* muv   = raw + 320;          // mean per feature
    float* rsv   = raw + 352;          // rcp(std) per feature (0 where std==0)
    float* stage = raw + 384;          // 1120 packed outputs

    const float* src = in + (size_t)sid * (S * F);

    // ---- P1: global -> LDS (2 vector loads, coalesced; NT loads keep L2 clean) ----
    {
        fx4 v0 = __builtin_nontemporal_load((const fx4*)(src + 4 * lane));
        *(fx4*)(raw + 4 * lane) = v0;
        if (lane < 16) {
            fx4 v1 = __builtin_nontemporal_load((const fx4*)(src + 256 + 4 * lane));
            *(fx4*)(raw + 256 + 4 * lane) = v1;
        }
    }
    wave_sync();

    const int f    = lane & 31;
    const int half = lane >> 5;

    // ---- P2: ONE 10-read pass -> mean, var (E[x^2]-mu^2), std, z, ld, ret ----
    {
        float sum = 0.f, sumsq = 0.f, ldacc = 0.f, first = 0.f, last = 0.f;
        #pragma unroll
        for (int s = 0; s < S; ++s) {
            float v = raw[s * F + f];          // lane l and l+32: same addr (broadcast)
            sum   += v;
            sumsq += v * v;
            ldacc += (float)(s + 1) * v;
            if (s == 0)     first = v;
            if (s == S - 1) last  = v;
        }
        if (half == 0) {
            float mean = sum * 0.1f;
            float var  = fmaxf(sumsq * 0.1f - mean * mean, 0.0f);  // biased var
            float sd   = __builtin_amdgcn_sqrtf(var);
            float rs   = (sd == 0.0f) ? 0.0f : fast_rcp(sd);
            muv[f] = mean;
            rsv[f] = rs;
            stage[f]     = sd;                // std
            stage[F + f] = mean * rs;         // z = divide_no_nan(mean, std)
        } else {
            stage[2 * F + f] = ldacc * (1.0f / 55.0f);                // linspace(1,10)/55
            float ret = (first == 0.0f) ? 0.0f : last * fast_rcp(first);
            stage[3 * F + f] = ret - 1.0f;
        }
    }
    wave_sync();

    // ---- P5: pairwise products on RAW data; acc init = -10*mu_r*mu_c ----
    {
        const int rb = lane >> 3;   // 0..7
        const int cb = lane & 7;    // 0..7
        fx4 ma = *(fx4*)(muv + 4 * rb);
        fx4 mb = *(fx4*)(muv + 4 * cb);
        fx4 ra = *(fx4*)(rsv + 4 * rb);
        fx4 rc = *(fx4*)(rsv + 4 * cb);
        const float maa[4] = {ma.x, ma.y, ma.z, ma.w};
        const float mbb[4] = {mb.x, mb.y, mb.z, mb.w};
        const float raa[4] = {ra.x, ra.y, ra.z, ra.w};
        const float rcc[4] = {rc.x, rc.y, rc.z, rc.w};

        float acc[4][4];
        float nm[4];
        #pragma unroll
        for (int i = 0; i < 4; ++i) nm[i] = -10.0f * maa[i];
        #pragma unroll
        for (int i = 0; i < 4; ++i)
            #pragma unroll
            for (int j = 0; j < 4; ++j) acc[i][j] = nm[i] * mbb[j];

        #pragma unroll
        for (int s = 0; s < S; ++s) {
            fx4 a4 = *(fx4*)(raw + s * F + 4 * rb);   // 8 distinct addrs -> broadcast
            fx4 b4 = *(fx4*)(raw + s * F + 4 * cb);
            const float aa[4] = {a4.x, a4.y, a4.z, a4.w};
            const float bb[4] = {b4.x, b4.y, b4.z, b4.w};
            #pragma unroll
            for (int i = 0; i < 4; ++i)
                #pragma unroll
                for (int j = 0; j < 4; ++j)
                    acc[i][j] += aa[i] * bb[j];
        }

        #pragma unroll
        for (int i = 0; i < 4; ++i) {
            const int r = 4 * rb + i;
            #pragma unroll
            for (int j = 0; j < 4; ++j) {
                const int c = 4 * cb + j;
                if (r > c) {                        // strict lower triangle
                    const int p = (r * (r - 1)) / 2 + c;
                    float prod = acc[i][j];
                    stage[4 * F + p]         = prod * (1.0f / 9.0f);          // cov
                    stage[4 * F + NPAIR + p] = prod * 0.1f * raa[i] * rcc[j]; // corr
                }
            }
        }
    }
    wave_sync();

    // ---- P6: coalesced writeout via PLAIN stores (L2-evict streaming path) ----
    {
        float* dst = out + (size_t)sid * OUTW;
        #pragma unroll
        for (int k = 0; k < 5; ++k) {
            int idx4 = lane + 64 * k;
            if (idx4 < OUTW / 4) {
                fx4 v = *(fx4*)(stage + 4 * idx4);
                *(fx4*)(dst + 4 * idx4) = v;
            }
        }
    }
}

extern "C" void kernel_launch(void* const* d_in, const int* in_sizes, int n_in,
                              void* d_out, int out_size, void* d_ws, size_t ws_size,
                              hipStream_t stream)
{
    const float* in = (const float*)d_in[0];
    float* out      = (float*)d_out;
    const int nstrides = in_sizes[0] / (S * F);          // 122880
    const int grid     = (nstrides + WAVES - 1) / WAVES; // 30720
    fe_kernel<<<grid, 256, 0, stream>>>(in, out, nstrides);
}

// Round 11
// 143.406 us; speedup vs baseline: 1.0946x; 1.0946x over previous
//
#include <hip/hip_runtime.h>

// FeatureExpansion: per (b, ol) stride of 10x32 f32 -> 1120 f32 outputs
// [std(32) | z(32) | ld(32) | ret(32) | covf(496) | corrf(496)]
// One wave per stride; 4 waves per block; wave-local sync only.
//
// PINNED (R5/R6/R7 poison, ~10x HBM traffic amplification at 7-8 blocks/CU):
// __launch_bounds__(256,4), LDS = 24,064 B/block (6 blocks/CU). Do not slim.
// PINNED (R10): NT stores > plain stores (+14 us). NT loads kept.
// PINNED (R9): no persistent/prefetch - neutral. Flat grid.
// This round's single variable: P5 stage writes vectorized
// (8 x ds_write_b128 for full lower tiles instead of 32 x ds_write_b32).

typedef float fx4  __attribute__((ext_vector_type(4)));
typedef float fx4u __attribute__((ext_vector_type(4), aligned(4)));
typedef float fx3u __attribute__((ext_vector_type(3), aligned(4)));
typedef float fx2u __attribute__((ext_vector_type(2), aligned(4)));

constexpr int S      = 10;
constexpr int F      = 32;
constexpr int NPAIR  = 496;     // F*(F-1)/2
constexpr int OUTW   = 1120;    // 4*F + 2*NPAIR
constexpr int WAVES  = 4;
// per-wave LDS slice (floats): raw[320] | mu[32] | rs[32] | stage[1120]
constexpr int SLICE  = 320 + 64 + OUTW;   // 1504 floats = 6016 B; block = 24,064 B

// Wave-local barrier (each wave touches only its own LDS slice).
__device__ __forceinline__ void wave_sync() {
    asm volatile("s_waitcnt lgkmcnt(0)" ::: "memory");
    __builtin_amdgcn_sched_barrier(0);
}
__device__ __forceinline__ float fast_rcp(float x) { return __builtin_amdgcn_rcpf(x); }

__global__ __launch_bounds__(256, 4)
void fe_kernel(const float* __restrict__ in, float* __restrict__ out, int nstrides)
{
    __shared__ float lds[WAVES * SLICE];

    const int wv   = threadIdx.x >> 6;
    const int lane = threadIdx.x & 63;
    int sid = blockIdx.x * WAVES + wv;
    if (sid >= nstrides) sid = nstrides - 1;   // grid divides exactly for this shape

    float* raw   = &lds[wv * SLICE];   // 10x32 raw tile
    float* muv   = raw + 320;          // mean per feature
    float* rsv   = raw + 352;          // rcp(std) per feature (0 where std==0)
    float* stage = raw + 384;          // 1120 packed outputs

    const float* src = in + (size_t)sid * (S * F);

    // ---- P1: global -> LDS (2 vector loads, coalesced; NT loads keep L2 clean) ----
    {
        fx4 v0 = __builtin_nontemporal_load((const fx4*)(src + 4 * lane));
        *(fx4*)(raw + 4 * lane) = v0;
        if (lane < 16) {
            fx4 v1 = __builtin_nontemporal_load((const fx4*)(src + 256 + 4 * lane));
            *(fx4*)(raw + 256 + 4 * lane) = v1;
        }
    }
    wave_sync();

    const int f    = lane & 31;
    const int half = lane >> 5;

    // ---- P2: ONE 10-read pass -> mean, var (E[x^2]-mu^2), std, z, ld, ret ----
    {
        float sum = 0.f, sumsq = 0.f, ldacc = 0.f, first = 0.f, last = 0.f;
        #pragma unroll
        for (int s = 0; s < S; ++s) {
            float v = raw[s * F + f];          // lane l and l+32: same addr (broadcast)
            sum   += v;
            sumsq += v * v;
            ldacc += (float)(s + 1) * v;
            if (s == 0)     first = v;
            if (s == S - 1) last  = v;
        }
        if (half == 0) {
            float mean = sum * 0.1f;
            float var  = fmaxf(sumsq * 0.1f - mean * mean, 0.0f);  // biased var
            float sd   = __builtin_amdgcn_sqrtf(var);
            float rs   = (sd == 0.0f) ? 0.0f : fast_rcp(sd);
            muv[f] = mean;
            rsv[f] = rs;
            stage[f]     = sd;                // std
            stage[F + f] = mean * rs;         // z = divide_no_nan(mean, std)
        } else {
            stage[2 * F + f] = ldacc * (1.0f / 55.0f);                // linspace(1,10)/55
            float ret = (first == 0.0f) ? 0.0f : last * fast_rcp(first);
            stage[3 * F + f] = ret - 1.0f;
        }
    }
    wave_sync();

    // ---- P5: pairwise products on RAW data; acc init = -10*mu_r*mu_c;
    //          vectorized stage writes (b128 per packed row for full tiles) ----
    {
        const int rb = lane >> 3;   // 0..7
        const int cb = lane & 7;    // 0..7
        fx4 ma = *(fx4*)(muv + 4 * rb);
        fx4 mb = *(fx4*)(muv + 4 * cb);
        fx4 ra = *(fx4*)(rsv + 4 * rb);
        fx4 rc = *(fx4*)(rsv + 4 * cb);
        const float maa[4] = {ma.x, ma.y, ma.z, ma.w};
        const float mbb[4] = {mb.x, mb.y, mb.z, mb.w};
        const float raa[4] = {ra.x, ra.y, ra.z, ra.w};
        const float rcc[4] = {rc.x, rc.y, rc.z, rc.w};

        float acc[4][4];
        #pragma unroll
        for (int i = 0; i < 4; ++i) {
            float nm = -10.0f * maa[i];
            #pragma unroll
            for (int j = 0; j < 4; ++j) acc[i][j] = nm * mbb[j];
        }

        #pragma unroll
        for (int s = 0; s < S; ++s) {
            fx4 a4 = *(fx4*)(raw + s * F + 4 * rb);   // 8 distinct addrs -> broadcast
            fx4 b4 = *(fx4*)(raw + s * F + 4 * cb);
            const float aa[4] = {a4.x, a4.y, a4.z, a4.w};
            const float bb[4] = {b4.x, b4.y, b4.z, b4.w};
            #pragma unroll
            for (int i = 0; i < 4; ++i)
                #pragma unroll
                for (int j = 0; j < 4; ++j)
                    acc[i][j] += aa[i] * bb[j];
        }

        float* stgc = stage + 4 * F;            // cov packed lower-tri
        float* stgr = stage + 4 * F + NPAIR;    // corr packed lower-tri

        if (rb > cb) {
            // full lower tile: each row = 4 consecutive packed indices -> b128 writes
            #pragma unroll
            for (int i = 0; i < 4; ++i) {
                const int r = 4 * rb + i;
                const int p = (r * (r - 1)) / 2 + 4 * cb;
                fx4u cv = { acc[i][0], acc[i][1], acc[i][2], acc[i][3] };
                *(fx4u*)(stgc + p) = cv * (1.0f / 9.0f);
                const float sc = 0.1f * raa[i];
                fx4u cr = { acc[i][0] * rcc[0], acc[i][1] * rcc[1],
                            acc[i][2] * rcc[2], acc[i][3] * rcc[3] };
                *(fx4u*)(stgr + p) = cr * sc;
            }
        } else if (rb == cb) {
            const int base = 4 * rb;
            {   // row 1: 1 element
                const int r = base + 1;
                const int p = (r * (r - 1)) / 2 + base;
                stgc[p] = acc[1][0] * (1.0f / 9.0f);
                stgr[p] = acc[1][0] * 0.1f * raa[1] * rcc[0];
            }
            {   // row 2: 2 elements
                const int r = base + 2;
                const int p = (r * (r - 1)) / 2 + base;
                fx2u cv = { acc[2][0], acc[2][1] };
                *(fx2u*)(stgc + p) = cv * (1.0f / 9.0f);
                const float sc = 0.1f * raa[2];
                fx2u cr = { acc[2][0] * rcc[0], acc[2][1] * rcc[1] };
                *(fx2u*)(stgr + p) = cr * sc;
            }
            {   // row 3: 3 elements
                const int r = base + 3;
                const int p = (r * (r - 1)) / 2 + base;
                fx3u cv = { acc[3][0], acc[3][1], acc[3][2] };
                *(fx3u*)(stgc + p) = cv * (1.0f / 9.0f);
                const float sc = 0.1f * raa[3];
                fx3u cr = { acc[3][0] * rcc[0], acc[3][1] * rcc[1], acc[3][2] * rcc[2] };
                *(fx3u*)(stgr + p) = cr * sc;
            }
        }
        // rb < cb: upper-triangle tile, nothing to store
    }
    wave_sync();

    // ---- P6: coalesced NT writeout: 280 float4 per stride ----
    {
        float* dst = out + (size_t)sid * OUTW;
        #pragma unroll
        for (int k = 0; k < 5; ++k) {
            int idx4 = lane + 64 * k;
            if (idx4 < OUTW / 4) {
                fx4 v = *(fx4*)(stage + 4 * idx4);
                __builtin_nontemporal_store(v, (fx4*)(dst + 4 * idx4));
            }
        }
    }
}

extern "C" void kernel_launch(void* const* d_in, const int* in_sizes, int n_in,
                              void* d_out, int out_size, void* d_ws, size_t ws_size,
                              hipStream_t stream)
{
    const float* in = (const float*)d_in[0];
    float* out      = (float*)d_out;
    const int nstrides = in_sizes[0] / (S * F);          // 122880
    const int grid     = (nstrides + WAVES - 1) / WAVES; // 30720
    fe_kernel<<<grid, 256, 0, stream>>>(in, out, nstrides);
}

// Round 12
// 115.372 us; speedup vs baseline: 1.3606x; 1.2430x over previous
//
#include <hip/hip_runtime.h>

// FeatureExpansion: per (b, ol) stride of 10x32 f32 -> 1120 f32 outputs
// [std(32) | z(32) | ld(32) | ret(32) | covf(496) | corrf(496)]
// One wave per stride; 4 waves per block; wave-local sync only.
//
// PINNED (R5/R6/R7 poison, ~10x HBM traffic amplification at 7-8 blocks/CU):
// __launch_bounds__(256,4), LDS = 24,064 B/block (6 blocks/CU). Do not slim.
// PINNED (R10): NT stores > plain stores (+14 us).
// PINNED (R9): no persistent/prefetch - neutral. Flat grid.
// PINNED (R11): P5 write vectorization neutral (kept, harmless).
// This round's single variable: P1 loads PLAIN (not NT) so the 157 MB input
// (< 256 MB L3) can stay Infinity-Cache-resident across timed replays.

typedef float fx4  __attribute__((ext_vector_type(4)));
typedef float fx4u __attribute__((ext_vector_type(4), aligned(4)));
typedef float fx3u __attribute__((ext_vector_type(3), aligned(4)));
typedef float fx2u __attribute__((ext_vector_type(2), aligned(4)));

constexpr int S      = 10;
constexpr int F      = 32;
constexpr int NPAIR  = 496;     // F*(F-1)/2
constexpr int OUTW   = 1120;    // 4*F + 2*NPAIR
constexpr int WAVES  = 4;
// per-wave LDS slice (floats): raw[320] | mu[32] | rs[32] | stage[1120]
constexpr int SLICE  = 320 + 64 + OUTW;   // 1504 floats = 6016 B; block = 24,064 B

// Wave-local barrier (each wave touches only its own LDS slice).
__device__ __forceinline__ void wave_sync() {
    asm volatile("s_waitcnt lgkmcnt(0)" ::: "memory");
    __builtin_amdgcn_sched_barrier(0);
}
__device__ __forceinline__ float fast_rcp(float x) { return __builtin_amdgcn_rcpf(x); }

__global__ __launch_bounds__(256, 4)
void fe_kernel(const float* __restrict__ in, float* __restrict__ out, int nstrides)
{
    __shared__ float lds[WAVES * SLICE];

    const int wv   = threadIdx.x >> 6;
    const int lane = threadIdx.x & 63;
    int sid = blockIdx.x * WAVES + wv;
    if (sid >= nstrides) sid = nstrides - 1;   // grid divides exactly for this shape

    float* raw   = &lds[wv * SLICE];   // 10x32 raw tile
    float* muv   = raw + 320;          // mean per feature
    float* rsv   = raw + 352;          // rcp(std) per feature (0 where std==0)
    float* stage = raw + 384;          // 1120 packed outputs

    const float* src = in + (size_t)sid * (S * F);

    // ---- P1: global -> LDS (PLAIN loads: let L3 keep the input resident) ----
    {
        fx4 v0 = *(const fx4*)(src + 4 * lane);
        *(fx4*)(raw + 4 * lane) = v0;
        if (lane < 16) {
            fx4 v1 = *(const fx4*)(src + 256 + 4 * lane);
            *(fx4*)(raw + 256 + 4 * lane) = v1;
        }
    }
    wave_sync();

    const int f    = lane & 31;
    const int half = lane >> 5;

    // ---- P2: ONE 10-read pass -> mean, var (E[x^2]-mu^2), std, z, ld, ret ----
    {
        float sum = 0.f, sumsq = 0.f, ldacc = 0.f, first = 0.f, last = 0.f;
        #pragma unroll
        for (int s = 0; s < S; ++s) {
            float v = raw[s * F + f];          // lane l and l+32: same addr (broadcast)
            sum   += v;
            sumsq += v * v;
            ldacc += (float)(s + 1) * v;
            if (s == 0)     first = v;
            if (s == S - 1) last  = v;
        }
        if (half == 0) {
            float mean = sum * 0.1f;
            float var  = fmaxf(sumsq * 0.1f - mean * mean, 0.0f);  // biased var
            float sd   = __builtin_amdgcn_sqrtf(var);
            float rs   = (sd == 0.0f) ? 0.0f : fast_rcp(sd);
            muv[f] = mean;
            rsv[f] = rs;
            stage[f]     = sd;                // std
            stage[F + f] = mean * rs;         // z = divide_no_nan(mean, std)
        } else {
            stage[2 * F + f] = ldacc * (1.0f / 55.0f);                // linspace(1,10)/55
            float ret = (first == 0.0f) ? 0.0f : last * fast_rcp(first);
            stage[3 * F + f] = ret - 1.0f;
        }
    }
    wave_sync();

    // ---- P5: pairwise products on RAW data; acc init = -10*mu_r*mu_c;
    //          vectorized stage writes (b128 per packed row for full tiles) ----
    {
        const int rb = lane >> 3;   // 0..7
        const int cb = lane & 7;    // 0..7
        fx4 ma = *(fx4*)(muv + 4 * rb);
        fx4 mb = *(fx4*)(muv + 4 * cb);
        fx4 ra = *(fx4*)(rsv + 4 * rb);
        fx4 rc = *(fx4*)(rsv + 4 * cb);
        const float maa[4] = {ma.x, ma.y, ma.z, ma.w};
        const float mbb[4] = {mb.x, mb.y, mb.z, mb.w};
        const float raa[4] = {ra.x, ra.y, ra.z, ra.w};
        const float rcc[4] = {rc.x, rc.y, rc.z, rc.w};

        float acc[4][4];
        #pragma unroll
        for (int i = 0; i < 4; ++i) {
            float nm = -10.0f * maa[i];
            #pragma unroll
            for (int j = 0; j < 4; ++j) acc[i][j] = nm * mbb[j];
        }

        #pragma unroll
        for (int s = 0; s < S; ++s) {
            fx4 a4 = *(fx4*)(raw + s * F + 4 * rb);   // 8 distinct addrs -> broadcast
            fx4 b4 = *(fx4*)(raw + s * F + 4 * cb);
            const float aa[4] = {a4.x, a4.y, a4.z, a4.w};
            const float bb[4] = {b4.x, b4.y, b4.z, b4.w};
            #pragma unroll
            for (int i = 0; i < 4; ++i)
                #pragma unroll
                for (int j = 0; j < 4; ++j)
                    acc[i][j] += aa[i] * bb[j];
        }

        float* stgc = stage + 4 * F;            // cov packed lower-tri
        float* stgr = stage + 4 * F + NPAIR;    // corr packed lower-tri

        if (rb > cb) {
            // full lower tile: each row = 4 consecutive packed indices -> b128 writes
            #pragma unroll
            for (int i = 0; i < 4; ++i) {
                const int r = 4 * rb + i;
                const int p = (r * (r - 1)) / 2 + 4 * cb;
                fx4u cv = { acc[i][0], acc[i][1], acc[i][2], acc[i][3] };
                *(fx4u*)(stgc + p) = cv * (1.0f / 9.0f);
                const float sc = 0.1f * raa[i];
                fx4u cr = { acc[i][0] * rcc[0], acc[i][1] * rcc[1],
                            acc[i][2] * rcc[2], acc[i][3] * rcc[3] };
                *(fx4u*)(stgr + p) = cr * sc;
            }
        } else if (rb == cb) {
            const int base = 4 * rb;
            {   // row 1: 1 element
                const int r = base + 1;
                const int p = (r * (r - 1)) / 2 + base;
                stgc[p] = acc[1][0] * (1.0f / 9.0f);
                stgr[p] = acc[1][0] * 0.1f * raa[1] * rcc[0];
            }
            {   // row 2: 2 elements
                const int r = base + 2;
                const int p = (r * (r - 1)) / 2 + base;
                fx2u cv = { acc[2][0], acc[2][1] };
                *(fx2u*)(stgc + p) = cv * (1.0f / 9.0f);
                const float sc = 0.1f * raa[2];
                fx2u cr = { acc[2][0] * rcc[0], acc[2][1] * rcc[1] };
                *(fx2u*)(stgr + p) = cr * sc;
            }
            {   // row 3: 3 elements
                const int r = base + 3;
                const int p = (r * (r - 1)) / 2 + base;
                fx3u cv = { acc[3][0], acc[3][1], acc[3][2] };
                *(fx3u*)(stgc + p) = cv * (1.0f / 9.0f);
                const float sc = 0.1f * raa[3];
                fx3u cr = { acc[3][0] * rcc[0], acc[3][1] * rcc[1], acc[3][2] * rcc[2] };
                *(fx3u*)(stgr + p) = cr * sc;
            }
        }
        // rb < cb: upper-triangle tile, nothing to store
    }
    wave_sync();

    // ---- P6: coalesced NT writeout: 280 float4 per stride ----
    {
        float* dst = out + (size_t)sid * OUTW;
        #pragma unroll
        for (int k = 0; k < 5; ++k) {
            int idx4 = lane + 64 * k;
            if (idx4 < OUTW / 4) {
                fx4 v = *(fx4*)(stage + 4 * idx4);
                __builtin_nontemporal_store(v, (fx4*)(dst + 4 * idx4));
            }
        }
    }
}

extern "C" void kernel_launch(void* const* d_in, const int* in_sizes, int n_in,
                              void* d_out, int out_size, void* d_ws, size_t ws_size,
                              hipStream_t stream)
{
    const float* in = (const float*)d_in[0];
    float* out      = (float*)d_out;
    const int nstrides = in_sizes[0] / (S * F);          // 122880
    const int grid     = (nstrides + WAVES - 1) / WAVES; // 30720
    fe_kernel<<<grid, 256, 0, stream>>>(in, out, nstrides);
}

// Round 13
// 114.549 us; speedup vs baseline: 1.3703x; 1.0072x over previous
//
#include <hip/hip_runtime.h>

// FeatureExpansion: per (b, ol) stride of 10x32 f32 -> 1120 f32 outputs
// [std(32) | z(32) | ld(32) | ret(32) | covf(496) | corrf(496)]
// One wave per stride; 4 waves per block; wave-local sync only.
//
// PINNED (R5/R6/R7 poison, ~10x HBM traffic amplification at 7-8 blocks/CU):
// __launch_bounds__(256,4), LDS = 24,064 B/block (6 blocks/CU). Do not slim.
// PINNED (R10): NT stores > plain stores (+14 us).
// PINNED (R12): PLAIN loads >> NT loads (-28 us; input is L3-fittable).
// PINNED (R9): no persistent/prefetch - neutral. Flat grid.
// PINNED (R11): P5 write vectorization neutral (kept, harmless).
// This round's single variable: bijective XCD block swizzle so each XCD
// owns one contiguous ~65 MB output region (write-stream L2/DRAM locality).

typedef float fx4  __attribute__((ext_vector_type(4)));
typedef float fx4u __attribute__((ext_vector_type(4), aligned(4)));
typedef float fx3u __attribute__((ext_vector_type(3), aligned(4)));
typedef float fx2u __attribute__((ext_vector_type(2), aligned(4)));

constexpr int S      = 10;
constexpr int F      = 32;
constexpr int NPAIR  = 496;     // F*(F-1)/2
constexpr int OUTW   = 1120;    // 4*F + 2*NPAIR
constexpr int WAVES  = 4;
constexpr int NXCD   = 8;
// per-wave LDS slice (floats): raw[320] | mu[32] | rs[32] | stage[1120]
constexpr int SLICE  = 320 + 64 + OUTW;   // 1504 floats = 6016 B; block = 24,064 B

// Wave-local barrier (each wave touches only its own LDS slice).
__device__ __forceinline__ void wave_sync() {
    asm volatile("s_waitcnt lgkmcnt(0)" ::: "memory");
    __builtin_amdgcn_sched_barrier(0);
}
__device__ __forceinline__ float fast_rcp(float x) { return __builtin_amdgcn_rcpf(x); }

__global__ __launch_bounds__(256, 4)
void fe_kernel(const float* __restrict__ in, float* __restrict__ out,
               int nstrides, int nwg)
{
    __shared__ float lds[WAVES * SLICE];

    const int wv   = threadIdx.x >> 6;
    const int lane = threadIdx.x & 63;

    // Bijective XCD swizzle (nwg % 8 == 0 for this shape): XCD k (= bid%8 by
    // round-robin dispatch) gets the contiguous block range [k*nwg/8, ...).
    const int cpx = nwg / NXCD;
    const int swz = (blockIdx.x % NXCD) * cpx + (blockIdx.x / NXCD);

    int sid = swz * WAVES + wv;
    if (sid >= nstrides) sid = nstrides - 1;   // grid divides exactly for this shape

    float* raw   = &lds[wv * SLICE];   // 10x32 raw tile
    float* muv   = raw + 320;          // mean per feature
    float* rsv   = raw + 352;          // rcp(std) per feature (0 where std==0)
    float* stage = raw + 384;          // 1120 packed outputs

    const float* src = in + (size_t)sid * (S * F);

    // ---- P1: global -> LDS (PLAIN loads: L3 serves the 157 MB input) ----
    {
        fx4 v0 = *(const fx4*)(src + 4 * lane);
        *(fx4*)(raw + 4 * lane) = v0;
        if (lane < 16) {
            fx4 v1 = *(const fx4*)(src + 256 + 4 * lane);
            *(fx4*)(raw + 256 + 4 * lane) = v1;
        }
    }
    wave_sync();

    const int f    = lane & 31;
    const int half = lane >> 5;

    // ---- P2: ONE 10-read pass -> mean, var (E[x^2]-mu^2), std, z, ld, ret ----
    {
        float sum = 0.f, sumsq = 0.f, ldacc = 0.f, first = 0.f, last = 0.f;
        #pragma unroll
        for (int s = 0; s < S; ++s) {
            float v = raw[s * F + f];          // lane l and l+32: same addr (broadcast)
            sum   += v;
            sumsq += v * v;
            ldacc += (float)(s + 1) * v;
            if (s == 0)     first = v;
            if (s == S - 1) last  = v;
        }
        if (half == 0) {
            float mean = sum * 0.1f;
            float var  = fmaxf(sumsq * 0.1f - mean * mean, 0.0f);  // biased var
            float sd   = __builtin_amdgcn_sqrtf(var);
            float rs   = (sd == 0.0f) ? 0.0f : fast_rcp(sd);
            muv[f] = mean;
            rsv[f] = rs;
            stage[f]     = sd;                // std
            stage[F + f] = mean * rs;         // z = divide_no_nan(mean, std)
        } else {
            stage[2 * F + f] = ldacc * (1.0f / 55.0f);                // linspace(1,10)/55
            float ret = (first == 0.0f) ? 0.0f : last * fast_rcp(first);
            stage[3 * F + f] = ret - 1.0f;
        }
    }
    wave_sync();

    // ---- P5: pairwise products on RAW data; acc init = -10*mu_r*mu_c;
    //          vectorized stage writes (b128 per packed row for full tiles) ----
    {
        const int rb = lane >> 3;   // 0..7
        const int cb = lane & 7;    // 0..7
        fx4 ma = *(fx4*)(muv + 4 * rb);
        fx4 mb = *(fx4*)(muv + 4 * cb);
        fx4 ra = *(fx4*)(rsv + 4 * rb);
        fx4 rc = *(fx4*)(rsv + 4 * cb);
        const float maa[4] = {ma.x, ma.y, ma.z, ma.w};
        const float mbb[4] = {mb.x, mb.y, mb.z, mb.w};
        const float raa[4] = {ra.x, ra.y, ra.z, ra.w};
        const float rcc[4] = {rc.x, rc.y, rc.z, rc.w};

        float acc[4][4];
        #pragma unroll
        for (int i = 0; i < 4; ++i) {
            float nm = -10.0f * maa[i];
            #pragma unroll
            for (int j = 0; j < 4; ++j) acc[i][j] = nm * mbb[j];
        }

        #pragma unroll
        for (int s = 0; s < S; ++s) {
            fx4 a4 = *(fx4*)(raw + s * F + 4 * rb);   // 8 distinct addrs -> broadcast
            fx4 b4 = *(fx4*)(raw + s * F + 4 * cb);
            const float aa[4] = {a4.x, a4.y, a4.z, a4.w};
            const float bb[4] = {b4.x, b4.y, b4.z, b4.w};
            #pragma unroll
            for (int i = 0; i < 4; ++i)
                #pragma unroll
                for (int j = 0; j < 4; ++j)
                    acc[i][j] += aa[i] * bb[j];
        }

        float* stgc = stage + 4 * F;            // cov packed lower-tri
        float* stgr = stage + 4 * F + NPAIR;    // corr packed lower-tri

        if (rb > cb) {
            // full lower tile: each row = 4 consecutive packed indices -> b128 writes
            #pragma unroll
            for (int i = 0; i < 4; ++i) {
                const int r = 4 * rb + i;
                const int p = (r * (r - 1)) / 2 + 4 * cb;
                fx4u cv = { acc[i][0], acc[i][1], acc[i][2], acc[i][3] };
                *(fx4u*)(stgc + p) = cv * (1.0f / 9.0f);
                const float sc = 0.1f * raa[i];
                fx4u cr = { acc[i][0] * rcc[0], acc[i][1] * rcc[1],
                            acc[i][2] * rcc[2], acc[i][3] * rcc[3] };
                *(fx4u*)(stgr + p) = cr * sc;
            }
        } else if (rb == cb) {
            const int base = 4 * rb;
            {   // row 1: 1 element
                const int r = base + 1;
                const int p = (r * (r - 1)) / 2 + base;
                stgc[p] = acc[1][0] * (1.0f / 9.0f);
                stgr[p] = acc[1][0] * 0.1f * raa[1] * rcc[0];
            }
            {   // row 2: 2 elements
                const int r = base + 2;
                const int p = (r * (r - 1)) / 2 + base;
                fx2u cv = { acc[2][0], acc[2][1] };
                *(fx2u*)(stgc + p) = cv * (1.0f / 9.0f);
                const float sc = 0.1f * raa[2];
                fx2u cr = { acc[2][0] * rcc[0], acc[2][1] * rcc[1] };
                *(fx2u*)(stgr + p) = cr * sc;
            }
            {   // row 3: 3 elements
                const int r = base + 3;
                const int p = (r * (r - 1)) / 2 + base;
                fx3u cv = { acc[3][0], acc[3][1], acc[3][2] };
                *(fx3u*)(stgc + p) = cv * (1.0f / 9.0f);
                const float sc = 0.1f * raa[3];
                fx3u cr = { acc[3][0] * rcc[0], acc[3][1] * rcc[1], acc[3][2] * rcc[2] };
                *(fx3u*)(stgr + p) = cr * sc;
            }
        }
        // rb < cb: upper-triangle tile, nothing to store
    }
    wave_sync();

    // ---- P6: coalesced NT writeout: 280 float4 per stride ----
    {
        float* dst = out + (size_t)sid * OUTW;
        #pragma unroll
        for (int k = 0; k < 5; ++k) {
            int idx4 = lane + 64 * k;
            if (idx4 < OUTW / 4) {
                fx4 v = *(fx4*)(stage + 4 * idx4);
                __builtin_nontemporal_store(v, (fx4*)(dst + 4 * idx4));
            }
        }
    }
}

extern "C" void kernel_launch(void* const* d_in, const int* in_sizes, int n_in,
                              void* d_out, int out_size, void* d_ws, size_t ws_size,
                              hipStream_t stream)
{
    const float* in = (const float*)d_in[0];
    float* out      = (float*)d_out;
    const int nstrides = in_sizes[0] / (S * F);          // 122880
    const int grid     = (nstrides + WAVES - 1) / WAVES; // 30720 (divisible by 8)
    fe_kernel<<<grid, 256, 0, stream>>>(in, out, nstrides, grid);
}